// Round 4
// baseline (185.756 us; speedup 1.0000x reference)
//
#include <hip/hip_runtime.h>
#include <hip/hip_bf16.h>
#include <math.h>

#define BDIM 8192
#define DDIM 2048
#define CDIM 1000
#define BK   64

// ws layout (bytes):
//   Bt bf16 [1024*2048] =  4194304 @ 0
//   P0 bf16 [8192*1000] = 16384000 @ 4194304    (split-K partial, k-half 0)
//   P1 bf16 [8192*1000] = 16384000 @ 20578304   (split-K partial, k-half 1)
// total = 36962304  (xb eliminated: x is converted inside the GEMM)
#define WS_P0_OFFSET  4194304ULL
#define WS_P1_OFFSET  20578304ULL

typedef __attribute__((ext_vector_type(8))) short short8;
typedef __attribute__((ext_vector_type(4))) float floatx4;

__device__ __forceinline__ unsigned short f2bf(float f) {
    union { float f; unsigned u; } a; a.f = f;
    unsigned u = a.u;
    u = (u + 0x7fff + ((u >> 16) & 1)) >> 16;   // RNE, finite inputs
    return (unsigned short)u;
}

__device__ __forceinline__ float bf2f(unsigned short h) {
    union { unsigned u; float f; } a; a.u = ((unsigned)h) << 16;
    return a.f;
}

__device__ __forceinline__ void async_copy16(const void* gp, void* lp) {
    __builtin_amdgcn_global_load_lds(
        (const __attribute__((address_space(1))) void*)gp,
        (__attribute__((address_space(3))) void*)lp,
        16, 0, 0);
}

// ---- kernel 1: W -> Bt transpose only (x-conversion is fused into GEMM) ----
__global__ __launch_bounds__(256) void cvt_w_kernel(
    const float* __restrict__ W, unsigned short* __restrict__ Bt)
{
    __shared__ float tile[32][33];
    const int b2 = blockIdx.x;           // 64 k-tiles x 32 n-tiles
    const int t  = threadIdx.x;
    const int k0 = (b2 & 63) * 32;
    const int n0 = (b2 >> 6) * 32;
    const int tx = t & 31, ty = t >> 5;  // 32 x 8
    #pragma unroll
    for (int i = 0; i < 4; i++) {
        int k = k0 + ty + i * 8;
        int n = n0 + tx;
        tile[ty + i * 8][tx] = (n < CDIM) ? W[(size_t)k * CDIM + n] : 0.0f;
    }
    __syncthreads();
    #pragma unroll
    for (int i = 0; i < 4; i++) {
        int n = n0 + ty + i * 8;
        int k = k0 + tx;
        Bt[(size_t)n * DDIM + k] = f2bf(tile[tx][ty + i * 8]);
    }
}

// =====================================================================
// 4-region 256x256 split-K GEMM with FUSED A-conversion (R4).
// A is read directly from x (f32), converted to bf16 in-register, and
// ds_write_b128'd into the XOR-swizzled LDS layout (bit-identical to
// the old cvt+global_load_lds path).  B stays on global_load_lds.
//
// Per iteration j (tile j in buf(j&1)=cA/cB, tile j+1 in the other):
//  q0: issue A-u0(j+2) f32 loads ; MFMA(0,0) ; ds_read bf1(j)
//  q1: gload B-u0(j+2) ; issue A-u1(j+2) f32 loads ; MFMA(0,1) ;
//      ds_read af1(j)
//  q2: gload B-u1(j+2) ; vmcnt(8) [confirms B(j+1)+A-u0] ; cvt+write
//      A-u0(j+2) ; MFMA(1,0)
//  q3: vmcnt(4) [confirms A-u1] ; cvt+write A-u1(j+2) ; MFMA(1,1) ;
//      pre-read af0/bf0(j+1) ; lgkmcnt(0) ; barrier
// vmcnt invariant at iter start: B(j+1)x4 outstanding.  Issue order per
// iter: [Au0 x4, Au1 x4 + Bu0 x2, Bu1 x2] -> q2's vmcnt(8) retires
// B(j+1)x4+Au0x4 (FIFO), q3's vmcnt(4) retires Au1x4, leaving B(j+2)x4.
// Hazards: every LDS overwrite is >=2 barriers after its readers'
// completion (readers complete via MFMA-operand lgkm waits or the q3
// lgkmcnt(0); writes issue after the intervening barrier).
// =====================================================================

#define HBUF (256 * BK)   // ushorts per buffer half (32 KiB)

#define STAGE_B2(BASE, EXT, KO)                                               \
    do {                                                                      \
        _Pragma("unroll")                                                     \
        for (int h = 0; h < 2; h++) {                                         \
            const int row_ = rB0 + (EXT) + h * 128;                           \
            async_copy16(gB + (size_t)row_ * DDIM + (KO),                     \
                         (BASE) + row_ * BK + c8);                            \
        }                                                                     \
    } while (0)

// issue 4 float4 loads (rows q0+EXT, q0+EXT+128) into axr[SL..SL+3]
#define ISSUE_A(SL, EXT, KO)                                                  \
    do {                                                                      \
        const float* p0_ = gAf + (size_t)(q0 + (EXT)) * DDIM + (KO);          \
        const float* p1_ = p0_ + (size_t)128 * DDIM;                          \
        axr[(SL) + 0] = *(const float4*)(p0_);                                \
        axr[(SL) + 1] = *(const float4*)(p0_ + 4);                            \
        axr[(SL) + 2] = *(const float4*)(p1_);                                \
        axr[(SL) + 3] = *(const float4*)(p1_ + 4);                            \
    } while (0)

// convert axr[SL..SL+3] and store to swizzled LDS slot (dst chunk csw)
#define WRITE_A(BASE, SL, EXT)                                                \
    do {                                                                      \
        _Pragma("unroll")                                                     \
        for (int r_ = 0; r_ < 2; r_++) {                                      \
            const int row_ = q0 + (EXT) + r_ * 128;                           \
            float4 lo_ = axr[(SL) + r_ * 2];                                  \
            float4 hi_ = axr[(SL) + r_ * 2 + 1];                              \
            short8 pk_;                                                       \
            pk_[0] = (short)f2bf(lo_.x); pk_[1] = (short)f2bf(lo_.y);         \
            pk_[2] = (short)f2bf(lo_.z); pk_[3] = (short)f2bf(lo_.w);         \
            pk_[4] = (short)f2bf(hi_.x); pk_[5] = (short)f2bf(hi_.y);         \
            pk_[6] = (short)f2bf(hi_.z); pk_[7] = (short)f2bf(hi_.w);         \
            *(short8*)((BASE) + row_ * BK + csw) = pk_;                       \
        }                                                                     \
    } while (0)

#define LOADA_(BASE, MQ)                                                      \
    do {                                                                      \
        _Pragma("unroll")                                                     \
        for (int mf = 0; mf < 4; mf++) {                                      \
            const int r_ = (arA + (MQ) * 64 + mf * 16) * BK;                  \
            af[mf][0] = *(const short8*)((BASE) + r_ + xorb0);                \
            af[mf][1] = *(const short8*)((BASE) + r_ + xorb1);                \
        }                                                                     \
    } while (0)

#define LOADB_(BASE, NQ, BF)                                                  \
    do {                                                                      \
        _Pragma("unroll")                                                     \
        for (int nf = 0; nf < 2; nf++) {                                      \
            const int r_ = (arB + (NQ) * 32 + nf * 16) * BK;                  \
            BF[nf][0] = *(const short8*)((BASE) + r_ + xorb0);                \
            BF[nf][1] = *(const short8*)((BASE) + r_ + xorb1);                \
        }                                                                     \
    } while (0)

#define MMAC(MQ, NQ, BF)                                                      \
    do {                                                                      \
        __builtin_amdgcn_s_setprio(1);                                        \
        _Pragma("unroll")                                                     \
        for (int mf = 0; mf < 4; mf++) {                                      \
            _Pragma("unroll")                                                 \
            for (int nf = 0; nf < 2; nf++) {                                  \
                floatx4 c_ = acc[(MQ) * 4 + mf][(NQ) * 2 + nf];               \
                c_ = __builtin_amdgcn_mfma_f32_16x16x32_bf16(                 \
                    af[mf][0], BF[nf][0], c_, 0, 0, 0);                       \
                c_ = __builtin_amdgcn_mfma_f32_16x16x32_bf16(                 \
                    af[mf][1], BF[nf][1], c_, 0, 0, 0);                       \
                acc[(MQ) * 4 + mf][(NQ) * 2 + nf] = c_;                       \
            }                                                                 \
        }                                                                     \
        __builtin_amdgcn_s_setprio(0);                                        \
    } while (0)

#define RAW_BARRIER() asm volatile("s_barrier" ::: "memory")
#define WAIT_VM(N)    asm volatile("s_waitcnt vmcnt(" #N ")" ::: "memory")
#define WAIT_LGKM0()  asm volatile("s_waitcnt lgkmcnt(0)" ::: "memory")

__global__ __launch_bounds__(512) void gemm8_kernel(
    const float* __restrict__ X,
    const unsigned short* __restrict__ Bt,
    unsigned short* __restrict__ P0, unsigned short* __restrict__ P1)
{
    __shared__ unsigned short As[2 * HBUF];
    __shared__ unsigned short Bs[2 * HBUF];

    const int t    = threadIdx.x;
    const int wave = t >> 6;
    const int lane = t & 63;
    const int wm   = wave >> 2;          // 0..1  (M half)
    const int wn   = wave & 3;           // 0..3  (N quarter)
    const int quad = lane >> 4;
    const int l16  = lane & 15;

    // XCD-swizzled block mapping: 256 blocks -> 8 XCDs x 32.
    const int L    = blockIdx.x;
    const int g    = (L & 7) * 32 + (L >> 3);   // bijective, nwg%8==0
    const int z    = g & 1;                     // K-split
    const int tid2 = g >> 1;                    // 0..127
    const int mBase = (tid2 >> 2) * 256;
    const int nBase = (tid2 & 3) * 256;
    const int kBase = z * (DDIM / 2);
    const int NTt   = (DDIM / 2) / BK;          // 16 K-tiles

    // --- staging precompute
    const int c8  = (t & 7) << 3;               // B dst chunk col (ushorts)
    const int q0  = t >> 3;                     // 0..63
    const int csw = (((t & 7) ^ (q0 & 7)) << 3);// swizzled chunk (A dst / B src)
    const int rB0 = q0 + (q0 & 32);             // B-u0 rows: rb, rb+128
    const float* gAf = X + (size_t)mBase * DDIM + kBase + ((t & 7) << 3);
    const unsigned short* gB = Bt + (size_t)nBase * DDIM + kBase + csw;

    // --- fragment-read precompute
    const int xorb0 = ((0 * 4 + quad) ^ (l16 & 7)) << 3;
    const int xorb1 = ((1 * 4 + quad) ^ (l16 & 7)) << 3;
    const int arA = wm * 128 + l16;
    const int arB = wn * 64 + l16;

    floatx4 acc[8][4] = {};
    short8 af[4][2], bf0[2][2], bf1[2][2];
    float4 axr[8];

    // --- prologue: tile0 A (load+cvt+write) + B0; tile1 A + B1.
    ISSUE_A(0, 0, 0);
    ISSUE_A(4, 64, 0);
    WAIT_VM(0);
    WRITE_A(As, 0, 0);
    WRITE_A(As, 4, 64);
    STAGE_B2(Bs, 0, 0);
    STAGE_B2(Bs, 32, 0);
    ISSUE_A(0, 0, BK);
    ISSUE_A(4, 64, BK);
    WAIT_VM(0);                 // drains B0 + tile1 A loads
    WRITE_A(As + HBUF, 0, 0);
    WRITE_A(As + HBUF, 4, 64);
    STAGE_B2(Bs + HBUF, 0, BK);
    STAGE_B2(Bs + HBUF, 32, BK);   // B1 x4 stays outstanding (invariant)
    WAIT_LGKM0();
    RAW_BARRIER();
    LOADA_(As, 0);
    LOADB_(Bs, 0, bf0);
    WAIT_LGKM0();
    RAW_BARRIER();

    for (int j = 0; j < NTt; j++) {
        const int bo = (j & 1) * HBUF;
        unsigned short* const cA = (unsigned short*)As + bo;
        unsigned short* const cB = (unsigned short*)Bs + bo;
        const unsigned short* const nA = (const unsigned short*)As + (bo ^ HBUF);
        const unsigned short* const nB = (const unsigned short*)Bs + (bo ^ HBUF);
        const int  ko2 = (j + 2) * BK;
        const bool s2  = (j + 2 < NTt);

        // q0: issue A-u0(j+2); MFMA(0,0); read bf1 (tile j)
        if (s2) ISSUE_A(0, 0, ko2);
        MMAC(0, 0, bf0);
        LOADB_(cB, 1, bf1);
        RAW_BARRIER();

        // q1: gload B-u0(j+2); issue A-u1(j+2); MFMA(0,1); read af1 (tile j)
        if (s2) STAGE_B2(cB, 0, ko2);
        if (s2) ISSUE_A(4, 64, ko2);
        MMAC(0, 1, bf1);
        LOADA_(cA, 1);
        RAW_BARRIER();

        // q2: gload B-u1(j+2); confirm B(j+1)+A-u0; cvt+write A-u0(j+2)
        if (s2) {
            STAGE_B2(cB, 32, ko2);
            WAIT_VM(8);
            WRITE_A(cA, 0, 0);
        }
        MMAC(1, 0, bf0);
        RAW_BARRIER();

        // q3: confirm A-u1; cvt+write A-u1(j+2); MFMA(1,1); pre-reads
        if (s2) {
            WAIT_VM(4);
            WRITE_A(cA, 4, 64);
        } else {
            WAIT_VM(0);         // tail: drain B(j+1) for the pre-reads
        }
        MMAC(1, 1, bf1);
        if (j + 1 < NTt) { LOADA_(nA, 0); LOADB_(nB, 0, bf0); }
        WAIT_LGKM0();
        RAW_BARRIER();
    }

    // --- epilogue: bf16 partial store (C row = quad*4+reg, col = l16)
    unsigned short* P = z ? P1 : P0;
    #pragma unroll
    for (int mfg = 0; mfg < 8; mfg++) {
        const int row0 = mBase + wm * 128 + mfg * 16 + quad * 4;
        #pragma unroll
        for (int nfg = 0; nfg < 4; nfg++) {
            const int col = nBase + wn * 64 + nfg * 16 + l16;
            if (col < CDIM) {
                #pragma unroll
                for (int rg = 0; rg < 4; rg++)
                    P[(size_t)(row0 + rg) * CDIM + col] = f2bf(acc[mfg][nfg][rg]);
            }
        }
    }
}

// ---- bias + LOO-logsumexp; sums two bf16 partials -> fp32 out ----
__global__ __launch_bounds__(256) void lse_kernel(
    float* __restrict__ out,
    const unsigned short* P0, const unsigned short* P1,
    const float* __restrict__ bias, int split)
{
    const int row = blockIdx.x;
    const int t   = threadIdx.x;
    __shared__ float red[8];

    const bool valid = t < (CDIM / 4);   // 250 threads x 4 cols
    const int c0 = t * 4;

    float4 v = make_float4(-INFINITY, -INFINITY, -INFINITY, -INFINITY);
    float4 e = make_float4(0.f, 0.f, 0.f, 0.f);
    if (valid) {
        if (split) {
            ushort4 p0 = *(const ushort4*)(P0 + (size_t)row * CDIM + c0);
            ushort4 p1 = *(const ushort4*)(P1 + (size_t)row * CDIM + c0);
            v.x = bf2f(p0.x) + bf2f(p1.x);
            v.y = bf2f(p0.y) + bf2f(p1.y);
            v.z = bf2f(p0.z) + bf2f(p1.z);
            v.w = bf2f(p0.w) + bf2f(p1.w);
        } else {
            v = *(const float4*)(out + (size_t)row * CDIM + c0);
        }
        float4 bb = *(const float4*)(bias + c0);
        v.x += bb.x; v.y += bb.y; v.z += bb.z; v.w += bb.w;
    }

    float m = fmaxf(fmaxf(v.x, v.y), fmaxf(v.z, v.w));
    #pragma unroll
    for (int off = 32; off > 0; off >>= 1)
        m = fmaxf(m, __shfl_down(m, off, 64));
    const int wave = t >> 6;
    if ((t & 63) == 0) red[wave] = m;
    __syncthreads();
    if (t == 0) red[4] = fmaxf(fmaxf(red[0], red[1]), fmaxf(red[2], red[3]));
    __syncthreads();
    const float M = red[4];

    float s = 0.f;
    if (valid) {
        e.x = expf(v.x - M); e.y = expf(v.y - M);
        e.z = expf(v.z - M); e.w = expf(v.w - M);
        s = e.x + e.y + e.z + e.w;
    }
    #pragma unroll
    for (int off = 32; off > 0; off >>= 1)
        s += __shfl_down(s, off, 64);
    if ((t & 63) == 0) red[wave] = s;
    __syncthreads();
    if (t == 0) red[4] = red[0] + red[1] + red[2] + red[3];
    __syncthreads();
    const float S    = red[4];
    const float lse  = M + logf(S);
    const float invS = 1.0f / S;

    if (valid) {
        float4 o;
        o.x = (v.x - lse) - log1pf(-e.x * invS);
        o.y = (v.y - lse) - log1pf(-e.y * invS);
        o.z = (v.z - lse) - log1pf(-e.z * invS);
        o.w = (v.w - lse) - log1pf(-e.w * invS);
        *(float4*)(out + (size_t)row * CDIM + c0) = o;
    }
}

extern "C" void kernel_launch(void* const* d_in, const int* in_sizes, int n_in,
                              void* d_out, int out_size, void* d_ws, size_t ws_size,
                              hipStream_t stream) {
    const float* x = (const float*)d_in[0];   // [8192, 2048]
    const float* W = (const float*)d_in[1];   // [2048, 1000]
    const float* b = (const float*)d_in[2];   // [1000]
    float* out = (float*)d_out;               // [8192, 1000]

    unsigned short* Bt = (unsigned short*)d_ws;
    unsigned short* P0 = (unsigned short*)((char*)d_ws + WS_P0_OFFSET);
    unsigned short* P1 = (unsigned short*)((char*)d_ws + WS_P1_OFFSET);

    // 1) W -> Bt transpose (tiny; x-conversion now fused into the GEMM)
    cvt_w_kernel<<<2048, 256, 0, stream>>>(W, Bt);

    // 2) split-K GEMM reading x (f32) directly
    gemm8_kernel<<<256, 512, 0, stream>>>(x, Bt, P0, P1);

    // 3) bias + LOO-LSE from the two bf16 partials
    lse_kernel<<<BDIM, 256, 0, stream>>>(out, P0, P1, b, 1);
}